// Round 6
// baseline (239.294 us; speedup 1.0000x reference)
//
#include <hip/hip_runtime.h>
#include <math.h>

// ---------------------------------------------------------------------------
// Problem constants
// ---------------------------------------------------------------------------
#define B_    4
#define CIN_  64
#define COUT_ 32
#define MOD_  128
#define VOX_  32768       // 32^3
#define UPVOX_ 262144     // 64^3
#define TAPS_ 27
#define EPS_  1e-8f

#define HALO_   816       // 4z * 6y * 34x halo voxels per 2z*4y*32x block
#define XUNITS_ 1632      // 2 halves-of-16ch * HALO_  (16-byte units per chunk)
#define CHUNK_HALVES_ 13824  // 16 cin * 27 taps * 32 oc

// Workspace layout (in floats)
#define WS_ALPHA 0        // 16 floats  [b][n]
#define WS_S     16       // 256 floats [b][i]
#define WS_WF16  512      // f16 weights: 4b*4c*13824 halves
#define WS_Y     111104   // 4*32*32768 floats, conv output
#define WS_V32   4305408  // 4*32768 floats, vox head at 32^3

// Output layout (floats in d_out)
#define OUT_YUP  0
#define OUT_VOX  33554432

typedef _Float16 half8 __attribute__((ext_vector_type(8)));
typedef float floatx16 __attribute__((ext_vector_type(16)));

// ---------------------------------------------------------------------------
// Kernel 1: alpha = softmax(style@sel_w.T + sel_b); s = style@affine_w.T + b
// ---------------------------------------------------------------------------
__global__ __launch_bounds__(256) void k_style(
    const float* __restrict__ style,     // [4][128]
    const float* __restrict__ affine_w,  // [64][128]
    const float* __restrict__ affine_b,  // [64]
    const float* __restrict__ sel_w,     // [4][128]
    const float* __restrict__ sel_b,     // [4]
    float* __restrict__ ws) {
  __shared__ float lg[16];
  const int tid = threadIdx.x;

  if (tid < 16) {
    const int b = tid >> 2, n = tid & 3;
    float l = sel_b[n];
    for (int k = 0; k < MOD_; ++k) l += style[b * MOD_ + k] * sel_w[n * MOD_ + k];
    lg[tid] = l;
  }
  __syncthreads();
  if (tid < 16) {
    const int b = tid >> 2;
    const float m = fmaxf(fmaxf(lg[b * 4 + 0], lg[b * 4 + 1]),
                          fmaxf(lg[b * 4 + 2], lg[b * 4 + 3]));
    float den = 0.f;
    for (int j = 0; j < 4; ++j) den += expf(lg[b * 4 + j] - m);
    ws[WS_ALPHA + tid] = expf(lg[tid] - m) / den;
  }
  {
    const int b = tid >> 6, i = tid & 63;
    float v = affine_b[i];
    for (int k = 0; k < MOD_; ++k) v += style[b * MOD_ + k] * affine_w[i * MOD_ + k];
    ws[WS_S + tid] = v;
  }
}

// ---------------------------------------------------------------------------
// Kernel 2: mix bank + modulate + demodulate; emit f16 weights in MFMA
// A-fragment order: wf[b][chunk c][tap t][half h][oc][j], cin i = c*16+h*8+j.
// ---------------------------------------------------------------------------
__global__ __launch_bounds__(256) void k_weights(
    const float* __restrict__ bank,   // [4][32][64][27]
    const float* __restrict__ ws_in,
    _Float16* __restrict__ wf) {
  const int b = blockIdx.x >> 5;
  const int o = blockIdx.x & 31;
  const int tid = threadIdx.x;
  __shared__ float red[256];

  float al[4];
#pragma unroll
  for (int n = 0; n < 4; ++n) al[n] = ws_in[WS_ALPHA + b * 4 + n];
  const float* sB = ws_in + WS_S + b * 64;

  float wv[7];
  float ss = 0.f;
#pragma unroll
  for (int r = 0; r < 7; ++r) {
    const int e = tid + r * 256;
    float v = 0.f;
    if (e < CIN_ * TAPS_) {
      const int i = e / TAPS_;
      const int t = e - i * TAPS_;
      const int base = (o * CIN_ + i) * TAPS_ + t;
      float bw = 0.f;
#pragma unroll
      for (int n = 0; n < 4; ++n)
        bw += al[n] * bank[base + n * (COUT_ * CIN_ * TAPS_)];
      v = bw * sB[i];
    }
    wv[r] = v;
    ss += v * v;
  }
  red[tid] = ss;
  __syncthreads();
  for (int st = 128; st > 0; st >>= 1) {
    if (tid < st) red[tid] += red[tid + st];
    __syncthreads();
  }
  const float demod = rsqrtf(red[0] + EPS_);

#pragma unroll
  for (int r = 0; r < 7; ++r) {
    const int e = tid + r * 256;
    if (e < CIN_ * TAPS_) {
      const int i = e / TAPS_;
      const int t = e - i * TAPS_;
      const int c = i >> 4, h = (i >> 3) & 1, j = i & 7;
      wf[((((b * 4 + c) * TAPS_ + t) * 2 + h) * 32 + o) * 8 + j] =
          (_Float16)(wv[r] * demod);
    }
  }
}

// ---------------------------------------------------------------------------
// Kernel 2b: pack x (f32 NCDHW) -> xt (f16, [b][34][34][34][64], zero-pad).
// Fully clamped addresses (never OOB); out-of-range taps multiplied to zero.
// xt lives in d_out scratch (k_up fully overwrites d_out afterwards).
// ---------------------------------------------------------------------------
__global__ __launch_bounds__(256) void k_pack(
    const float* __restrict__ x, _Float16* __restrict__ xt) {
  const int yp = blockIdx.x, zp = blockIdx.y, b = blockIdx.z;
  const int gz = zp - 1, gy = yp - 1;
  const bool zy_ok = ((unsigned)gz < 32u) && ((unsigned)gy < 32u);
  const int gzc = min(max(gz, 0), 31);
  const int gyc = min(max(gy, 0), 31);
  _Float16* dst = xt + (((size_t)(b * 34 + zp) * 34 + yp) * 34) * 64;
  const float* srow = x + ((size_t)b * CIN_) * VOX_ + gzc * 1024 + gyc * 32;
  for (int u = threadIdx.x; u < 34 * 8; u += 256) {
    const int xp = u >> 3, q = u & 7;
    const int gx = xp - 1;
    const bool ok = zy_ok && ((unsigned)gx < 32u);
    const float m = ok ? 1.0f : 0.0f;
    const int gxc = min(max(gx, 0), 31);
    half8 h;
#pragma unroll
    for (int i = 0; i < 8; ++i) {
      const float v = srow[(size_t)(q * 8 + i) * VOX_ + gxc];
      h[i] = (_Float16)(v * m);
    }
    *(half8*)&dst[xp * 64 + q * 8] = h;
  }
}

// ---------------------------------------------------------------------------
// Kernel 3: implicit-GEMM conv, mfma_f32_32x32x16_f16.
// Tile = 2z*4y*32x (512 blocks = 2/CU, 8 waves/CU). Wave = 2 output rows.
// A-fragments read directly from global wf (coalesced 1KB/instr, L2-hot).
// x halo double-buffered in LDS (52 KB), register-prefetch pipeline,
// one barrier per chunk. Per (dz,dx): 4 B-frags serve all 3 dy taps for
// both rows -> LDS-port cycles ~= MFMA cycles (balanced).
// Epilogue also computes v32 = vox_w . y (upsample commutes with 1x1 conv).
// ---------------------------------------------------------------------------
__global__ __launch_bounds__(256, 2) void k_conv(
    const _Float16* __restrict__ xt,   // [4][34][34][34][64]
    const _Float16* __restrict__ wf,   // [b][c][t][h][oc][8]
    const float* __restrict__ vox_w,   // [32]
    float* __restrict__ ws_y,          // [4][32][32768]
    float* __restrict__ v32) {         // [4][32768]
  __shared__ __align__(16) _Float16 xs[2][XUNITS_ * 8];   // 52224 B

  const int b  = blockIdx.y;
  const int bx = blockIdx.x;           // 128 blocks per batch
  const int z0 = (bx >> 3) * 2;
  const int y0 = (bx & 7) * 4;
  const int tid = threadIdx.x;
  const int w = tid >> 6;
  const int lane = tid & 63;
  const int hf = lane >> 5;
  const int col = lane & 31;
  const int lz = w >> 1;               // wave z row in tile (0..1)
  const int wy = (w & 1) * 2;          // wave y base in tile (0 or 2)

  const _Float16* xtb = xt + (size_t)b * (34 * 34 * 34 * 64);
  const _Float16* wfb = wf + (size_t)b * 4 * CHUNK_HALVES_;

  // Per-lane x-halo staging offsets (in halves) for units u = j*256 + tid:
  // u -> h = u/HALO_, hv = u%HALO_; hv -> (hz,hy,hx) in 4*6*34.
  int xoff[7];
  bool xok[7];
#pragma unroll
  for (int j = 0; j < 7; ++j) {
    const int u = j * 256 + tid;
    xok[j] = (u < XUNITS_);
    const int uc = xok[j] ? u : 0;
    const int h = uc / HALO_, hv = uc - h * HALO_;
    const int hz = hv / 204;
    const int rem = hv - hz * 204;
    const int hy = rem / 34;
    const int hx = rem - hy * 34;
    xoff[j] = (((z0 + hz) * 34 + (y0 + hy)) * 34 + hx) * 64 + h * 8;
  }

  floatx16 acc[2];
#pragma unroll
  for (int ay = 0; ay < 2; ++ay)
#pragma unroll
    for (int r = 0; r < 16; ++r) acc[ay][r] = 0.f;

  half8 xv[7];

  auto load_chunk = [&](int c) {
#pragma unroll
    for (int j = 0; j < 7; ++j)
      xv[j] = *(const half8*)(xtb + xoff[j] + c * 16);
  };
  auto write_chunk = [&](int bufi) {
#pragma unroll
    for (int j = 0; j < 7; ++j) {
      const int u = j * 256 + tid;
      if (xok[j]) *(half8*)&xs[bufi][u * 8] = xv[j];
    }
  };
  auto compute = [&](int bufi, int c) {
    const _Float16* xb_ = xs[bufi];
    // A-fragment base for this lane within chunk c: + t*512 per tap.
    const _Float16* wc = wfb + (size_t)c * CHUNK_HALVES_ + (hf * 32 + col) * 8;
#pragma unroll
    for (int dx = 0; dx < 3; ++dx) {
#pragma unroll
      for (int dz = 0; dz < 3; ++dz) {
        half8 Bf[4];
#pragma unroll
        for (int r = 0; r < 4; ++r) {
          const int hv = ((lz + dz) * 6 + (wy + r)) * 34 + dx + col;
          Bf[r] = *(const half8*)&xb_[(hf * HALO_ + hv) * 8];
        }
#pragma unroll
        for (int dy = 0; dy < 3; ++dy) {
          const int t = (dz * 3 + dy) * 3 + dx;
          const half8 af = *(const half8*)(wc + t * 512);
          acc[0] = __builtin_amdgcn_mfma_f32_32x32x16_f16(af, Bf[dy], acc[0], 0, 0, 0);
          acc[1] = __builtin_amdgcn_mfma_f32_32x32x16_f16(af, Bf[dy + 1], acc[1], 0, 0, 0);
        }
      }
    }
  };

  // Pipeline: one barrier per chunk; writes of chunk c+1 target the buffer
  // no wave is reading (previous barrier guarantees compute(c-1) finished).
  load_chunk(0);
  write_chunk(0);
  __syncthreads();
  for (int c = 0; c < 4; ++c) {
    if (c < 3) load_chunk(c + 1);
    compute(c & 1, c);
    if (c < 3) {
      write_chunk((c + 1) & 1);
      __syncthreads();
    }
  }

  // ---- epilogue: y stores + vox partial ----
  float vw[16];
#pragma unroll
  for (int r = 0; r < 16; ++r)
    vw[r] = vox_w[(r & 3) + 8 * (r >> 2) + 4 * hf];

  float* yb2 = ws_y + (size_t)b * COUT_ * VOX_;
  const int zz = z0 + lz;
#pragma unroll
  for (int ay = 0; ay < 2; ++ay) {
    const int yy = y0 + wy + ay;
    const int vbase = zz * 1024 + yy * 32 + col;
    float p = 0.f;
#pragma unroll
    for (int r = 0; r < 16; ++r) {
      const int oc = (r & 3) + 8 * (r >> 2) + 4 * hf;
      yb2[(size_t)oc * VOX_ + vbase] = acc[ay][r];
      p = fmaf(vw[r], acc[ay][r], p);
    }
    p += __shfl_xor(p, 32);
    if (hf == 0) v32[((size_t)b << 15) + vbase] = p;
  }
}

// ---------------------------------------------------------------------------
// Kernel 4: trilinear 2x upsample from LDS-staged z-planes. Grid:
// (32 z-pairs, 33 "channels" [32 y + v32], 4 b). Thread -> 2z*2y*8x brick.
// ---------------------------------------------------------------------------
__global__ __launch_bounds__(256) void k_up(
    const float* __restrict__ ws_y,   // [4][32][32768]
    const float* __restrict__ v32,    // [4][32768]
    const float* __restrict__ vox_b,  // [1]
    float* __restrict__ out) {
  __shared__ float P[3][1056];        // 3 z-planes, row stride 33 (bank-safe)
  const int kz = blockIdx.x;          // z-pair 0..31
  const int ch = blockIdx.y;          // 0..32 (32 == vox head)
  const int b = blockIdx.z;

  const int pzm = max(kz - 1, 0), pzp = min(kz + 1, 31);
  const float* src = (ch < 32) ? (ws_y + (((size_t)(b * 32 + ch)) << 15))
                               : (v32 + ((size_t)b << 15));
  for (int j = threadIdx.x; j < 768; j += 256) {
    const int p = j >> 8, idx = j & 255;
    const int r = idx >> 3, q = (idx & 7) * 4;
    const int zsrc = (p == 0) ? pzm : ((p == 1) ? kz : pzp);
    const float4 v = *(const float4*)(src + (zsrc << 10) + r * 32 + q);
    float* dp = &P[p][r * 33 + q];
    dp[0] = v.x; dp[1] = v.y; dp[2] = v.z; dp[3] = v.w;
  }
  __syncthreads();

  const int yp = threadIdx.x >> 3;    // 0..31 (y-pair)
  const int xq = threadIdx.x & 7;     // 0..7  (8 out-x per thread)
  const int ym = max(yp - 1, 0) * 33, yc = yp * 33, ypp = min(yp + 1, 31) * 33;

  int gxi[6];
#pragma unroll
  for (int i = 0; i < 6; ++i) gxi[i] = min(max(4 * xq - 1 + i, 0), 31);

  float ry[3][2][6];
#pragma unroll
  for (int p = 0; p < 3; ++p)
#pragma unroll
    for (int i = 0; i < 6; ++i) {
      const float a = P[p][ym + gxi[i]];
      const float bb = P[p][yc + gxi[i]];
      const float cc = P[p][ypp + gxi[i]];
      ry[p][0][i] = fmaf(0.25f, a, 0.75f * bb);
      ry[p][1][i] = fmaf(0.25f, cc, 0.75f * bb);
    }

  const float vb = (ch == 32) ? vox_b[0] : 0.f;
  float* base = out + ((ch < 32) ? (OUT_YUP + (((size_t)(b * 32 + ch)) * UPVOX_))
                                 : (OUT_VOX + (size_t)b * UPVOX_)) +
                (size_t)(2 * kz) * 4096 + (2 * yp) * 64 + 8 * xq;

#pragma unroll
  for (int zo = 0; zo < 2; ++zo)
#pragma unroll
    for (int yo = 0; yo < 2; ++yo) {
      float s[6];
#pragma unroll
      for (int i = 0; i < 6; ++i)
        s[i] = zo == 0 ? fmaf(0.25f, ry[0][yo][i], 0.75f * ry[1][yo][i])
                       : fmaf(0.25f, ry[2][yo][i], 0.75f * ry[1][yo][i]);
      float o[8];
#pragma unroll
      for (int ox = 0; ox < 8; ++ox) {
        const int k = ox >> 1;
        o[ox] = (ox & 1) ? fmaf(0.25f, s[k + 2], 0.75f * s[k + 1])
                         : fmaf(0.25f, s[k], 0.75f * s[k + 1]);
        o[ox] += vb;
      }
      float4* dst = (float4*)(base + (size_t)zo * 4096 + yo * 64);
      float4 v0; v0.x = o[0]; v0.y = o[1]; v0.z = o[2]; v0.w = o[3];
      float4 v1; v1.x = o[4]; v1.y = o[5]; v1.z = o[6]; v1.w = o[7];
      dst[0] = v0;
      dst[1] = v1;
    }
}

// ---------------------------------------------------------------------------
extern "C" void kernel_launch(void* const* d_in, const int* in_sizes, int n_in,
                              void* d_out, int out_size, void* d_ws, size_t ws_size,
                              hipStream_t stream) {
  const float* x        = (const float*)d_in[0];
  const float* style    = (const float*)d_in[1];
  const float* bank     = (const float*)d_in[2];
  const float* affine_w = (const float*)d_in[3];
  const float* affine_b = (const float*)d_in[4];
  const float* sel_w    = (const float*)d_in[5];
  const float* sel_b    = (const float*)d_in[6];
  const float* vox_w    = (const float*)d_in[7];
  const float* vox_b    = (const float*)d_in[8];
  float* out = (float*)d_out;
  float* ws  = (float*)d_ws;
  _Float16* wf16 = (_Float16*)(ws + WS_WF16);
  float* ws_y = ws + WS_Y;
  float* v32  = ws + WS_V32;
  // xt scratch lives at the front of d_out; k_up overwrites all of d_out.
  _Float16* xt = (_Float16*)d_out;

  k_style<<<1, 256, 0, stream>>>(style, affine_w, affine_b, sel_w, sel_b, ws);
  k_weights<<<128, 256, 0, stream>>>(bank, ws, wf16);
  k_pack<<<dim3(34, 34, B_), 256, 0, stream>>>(x, xt);
  k_conv<<<dim3(128, B_), 256, 0, stream>>>(xt, wf16, vox_w, ws_y, v32);
  k_up<<<dim3(32, 33, B_), 256, 0, stream>>>(ws_y, v32, vox_b, out);
}